// Round 10
// baseline (961.154 us; speedup 1.0000x reference)
//
#include <hip/hip_runtime.h>
#include <math.h>
#include <stdint.h>

#define Bz 64
#define Tz 32
#define Ez 64
#define Hz 256
#define Vz 32000
#define KTOT 320
#define NREP 64        // hT replicas (distinct-address broadcast)
#define REPF 16384     // floats per replica
#define PARF (NREP*REPF)

typedef unsigned long long u64;
typedef unsigned int u32;

__device__ __forceinline__ u32 map_f32(float f) {
  u32 u = __float_as_uint(f);
  return (u & 0x80000000u) ? ~u : (u | 0x80000000u);
}

__device__ __forceinline__ void gload_lds16(const float* g, float* l) {
  __builtin_amdgcn_global_load_lds(
      (const __attribute__((address_space(1))) void*)g,
      (__attribute__((address_space(3))) void*)l, 16, 0, 0);
}

// ---------------- weight repack: P4[j][k][g] (g = i,f,o,c); zero key bufs ----------------
__global__ void k_prep(const float* __restrict__ Wi, const float* __restrict__ Ui,
                       const float* __restrict__ Wf, const float* __restrict__ Uf,
                       const float* __restrict__ Wog, const float* __restrict__ Uog,
                       const float* __restrict__ Wc, const float* __restrict__ Uc,
                       float* __restrict__ P4, u64* __restrict__ key) {
  int j = blockIdx.x;        // 0..255
  int k = threadIdx.x;       // 0..319
  float g0, g1, g2, g3;
  if (k < Ez) {
    g0 = Wi[k*Hz + j]; g1 = Wf[k*Hz + j]; g2 = Wog[k*Hz + j]; g3 = Wc[k*Hz + j];
  } else {
    int kk = k - Ez;
    g0 = Ui[kk*Hz + j]; g1 = Uf[kk*Hz + j]; g2 = Uog[kk*Hz + j]; g3 = Uc[kk*Hz + j];
  }
  float* p = P4 + ((size_t)j*KTOT + k)*4;
  p[0] = g0; p[1] = g1; p[2] = g2; p[3] = g3;
  if (j == 0 && k < 2*Bz) key[k] = 0ull;
}

// ---------------- per-step LSTM cell: 32 blocks x 512 thr; wave = one j, lane = b --------
// R9 structure; only h I/O changed: read own replica, write NREP replicas.
__global__ __launch_bounds__(512) void k_gates(
    int t, const int* __restrict__ gnp,
    const int* __restrict__ input_x, const int* __restrict__ start_tok,
    const float* __restrict__ emb, const float* __restrict__ P4,
    const float* __restrict__ bi_, const float* __restrict__ bf_,
    const float* __restrict__ bog_, const float* __restrict__ bc_,
    const float* __restrict__ hTR_prev, float* __restrict__ hTR_cur,
    float* __restrict__ cT,
    const u64* __restrict__ key_prev, u64* __restrict__ key_cur,
    int* __restrict__ out) {
  extern __shared__ float xh[];          // [320][64] transposed, 80 KB
  __shared__ int tok_s[Bz];
  int tid = threadIdx.x;
  int blk = blockIdx.x;
  int gn = *gnp;

  if (tid < Bz) {
    int b = tid, tk;
    if (t == 0)          tk = start_tok[b];
    else if (t - 1 < gn) tk = input_x[b*Tz + (t-1)];
    else                 tk = (int)(~(u32)(key_prev[b] & 0xFFFFFFFFull));
    tok_s[b] = tk;
    if (blk == 0 && t > 0) out[b*Tz + (t-1)] = tk;
  }
  if (blk == 0 && tid >= 64 && tid < 64 + Bz) key_cur[tid - 64] = 0ull;
  __syncthreads();

  {
    int b = tid & 63, part = tid >> 6;           // part 0..7 -> k = part*8..+7
    const float4* e4 = (const float4*)(emb + (size_t)tok_s[b]*Ez + part*8);
    float4 v0 = e4[0], v1 = e4[1];
    int k0 = part*8;
    xh[(k0+0)*Bz + b] = v0.x; xh[(k0+1)*Bz + b] = v0.y;
    xh[(k0+2)*Bz + b] = v0.z; xh[(k0+3)*Bz + b] = v0.w;
    xh[(k0+4)*Bz + b] = v1.x; xh[(k0+5)*Bz + b] = v1.y;
    xh[(k0+6)*Bz + b] = v1.z; xh[(k0+7)*Bz + b] = v1.w;
  }
  if (t > 0) {
    // read this block's private replica (distinct addresses per block)
    const float4* s4 = (const float4*)(hTR_prev + (size_t)blk*REPF);
    float4* d4 = (float4*)(xh + Ez*Bz);
    #pragma unroll
    for (int i = 0; i < 8; ++i) d4[tid + i*512] = s4[tid + i*512];
  }
  __syncthreads();

  int lane = tid & 63;
  int j = __builtin_amdgcn_readfirstlane(blk*8 + (tid >> 6));
  const float* wj = P4 + (size_t)j*KTOT*4;
  float ai = bi_[j], af = bf_[j], ao = bog_[j], ac = bc_[j];

#define GQUAD(k0_) { \
    _Pragma("unroll") \
    for (int kk = 0; kk < 4; ++kk) { \
      float4 wv = *(const float4*)(wj + ((k0_)+kk)*4); \
      float xv = xh[((k0_)+kk)*Bz + lane]; \
      ai = fmaf(xv, wv.x, ai); af = fmaf(xv, wv.y, af); \
      ao = fmaf(xv, wv.z, ao); ac = fmaf(xv, wv.w, ac); } }

  #pragma unroll
  for (int k = 0; k < Ez; k += 4) GQUAD(k)
  if (t > 0) {
    #pragma unroll 8
    for (int k = Ez; k < KTOT; k += 4) GQUAD(k)
  }
#undef GQUAD

  float gi = 1.f/(1.f + expf(-ai));
  float gf = 1.f/(1.f + expf(-af));
  float go = 1.f/(1.f + expf(-ao));
  float gc = tanhf(ac);
  float cold = (t > 0) ? cT[j*Bz + lane] : 0.f;
  float cn = gf*cold + gi*gc;
  float hn = go * tanhf(cn);
  cT[j*Bz + lane] = cn;
  // write all replicas: hTR[r][j][b]
  {
    float* rep = hTR_cur + (size_t)j*Bz + lane;
    #pragma unroll
    for (int r = 0; r < NREP; ++r) rep[(size_t)r*REPF] = hn;
  }
}

// ---------------- logits: 250 blocks x 512 thr; barrier-free per-wave k-pipelines --------
// (byte-identical to round 9's passing k_logits except h staged from replica bid&63)
__global__ __launch_bounds__(512, 1) void k_logits(
    int t, const int* __restrict__ gnp,
    const float* __restrict__ hTR,       // replica base, parity cur
    const float* __restrict__ Wo, const float* __restrict__ bo,
    u64* __restrict__ key_cur) {         // 64 slots
  int gn = *gnp;
  if (t < gn) return;                    // uniform early-exit (teacher step)
  extern __shared__ float sm[];
  float* hLDS = sm;                      // 16384 f (64 KB)
  float* wbuf = sm + 16384;              // 16384 f (64 KB): 8 waves x 2 x 1024

  int tid = threadIdx.x;
  int bid = blockIdx.x;
  int wid = tid >> 6, lane = tid & 63;
  int seg = wid >> 1, chalf = wid & 1;
  int rg = lane >> 3, cg = lane & 7;

  float bo8[8];
  {
    const float4* b4 = (const float4*)(bo + bid*128 + chalf*64 + cg*8);
    float4 x = b4[0], y = b4[1];
    bo8[0]=x.x; bo8[1]=x.y; bo8[2]=x.z; bo8[3]=x.w;
    bo8[4]=y.x; bo8[5]=y.y; bo8[6]=y.z; bo8[7]=y.w;
  }
  // stage hT -> hLDS from this block's replica (distinct addresses across blocks)
  {
    const float4* s4 = (const float4*)(hTR + (size_t)(bid & (NREP-1))*REPF);
    float4* d4 = (float4*)hLDS;
    #pragma unroll
    for (int i = 0; i < 8; ++i) d4[tid + i*512] = s4[tid + i*512];
  }
  __syncthreads();

  float acc[8][8] = {};
  float* wb = wbuf + wid*2048;
  const float* gW = Wo + bid*128;

#define STAGE(q_, p_) { \
    int kb = seg*64 + (q_)*8; \
    _Pragma("unroll") \
    for (int i = 0; i < 4; ++i) { \
      int row = kb + i*2 + (lane>>5); \
      gload_lds16(gW + (size_t)row*Vz + ((lane&31)<<2), wb + (p_)*1024 + i*256); \
    } }

#define COMPUTE(q_, p_) { \
    const float* wp = wb + (p_)*1024; \
    const float* hp = hLDS + (seg*64 + (q_)*8)*Bz + rg*8; \
    _Pragma("unroll") \
    for (int kk = 0; kk < 8; ++kk) { \
      float4 h0 = *(const float4*)(hp + kk*Bz); \
      float4 h1 = *(const float4*)(hp + kk*Bz + 4); \
      float4 w0 = *(const float4*)(wp + kk*128 + chalf*64 + cg*8); \
      float4 w1 = *(const float4*)(wp + kk*128 + chalf*64 + cg*8 + 4); \
      float hv[8] = {h0.x,h0.y,h0.z,h0.w,h1.x,h1.y,h1.z,h1.w}; \
      float wv[8] = {w0.x,w0.y,w0.z,w0.w,w1.x,w1.y,w1.z,w1.w}; \
      _Pragma("unroll") \
      for (int r = 0; r < 8; ++r) { \
        _Pragma("unroll") \
        for (int c = 0; c < 8; ++c) acc[r][c] = fmaf(hv[r], wv[c], acc[r][c]); } \
    } }

  STAGE(0, 0)
  #pragma unroll 1
  for (int q = 0; q < 7; ++q) {
    STAGE(q+1, (q+1)&1)
    asm volatile("s_waitcnt vmcnt(4)" ::: "memory");   // oldest chunk landed; newest in flight
    __builtin_amdgcn_sched_barrier(0);
    COMPUTE(q, q&1)
  }
  asm volatile("s_waitcnt vmcnt(0)" ::: "memory");
  __builtin_amdgcn_sched_barrier(0);
  COMPUTE(7, 1)
#undef STAGE
#undef COMPUTE

  // ---- merge k-segment partials: (seg2,seg3) -> (seg0,seg1), then seg1 -> seg0 ----
  float* scratch = wbuf;                 // 4 regions x 4096 f
  __syncthreads();                       // all waves done with private wbuf
  if (wid >= 4) {
    float* r = scratch + (wid-4)*4096;
    #pragma unroll
    for (int i = 0; i < 64; ++i) r[i*64 + lane] = acc[i>>3][i&7];
  }
  __syncthreads();
  if (wid < 4) {
    const float* r = scratch + wid*4096;
    #pragma unroll
    for (int i = 0; i < 64; ++i) acc[i>>3][i&7] += r[i*64 + lane];
  }
  __syncthreads();
  if (wid == 2 || wid == 3) {
    float* r = scratch + (wid-2)*4096;
    #pragma unroll
    for (int i = 0; i < 64; ++i) r[i*64 + lane] = acc[i>>3][i&7];
  }
  __syncthreads();

  if (wid < 2) {
    const float* r = scratch + wid*4096;
    #pragma unroll
    for (int i = 0; i < 64; ++i) acc[i>>3][i&7] += r[i*64 + lane];

    // per-row argmax over this wave's 64 cols; first-index-wins
    int cbase = bid*128 + chalf*64 + cg*8;
    float myv = 0.f; int myi = 0;
    #pragma unroll
    for (int rr = 0; rr < 8; ++rr) {
      float bv = acc[rr][0] + bo8[0]; int bix = cbase;
      #pragma unroll
      for (int c = 1; c < 8; ++c) {
        float v = acc[rr][c] + bo8[c];
        if (v > bv) { bv = v; bix = cbase + c; }
      }
      #pragma unroll
      for (int m = 1; m < 8; m <<= 1) {
        float ov = __shfl_xor(bv, m, 64);
        int   oi = __shfl_xor(bix, m, 64);
        if (ov > bv || (ov == bv && oi < bix)) { bv = ov; bix = oi; }
      }
      if (cg == rr) { myv = bv; myi = bix; }
    }
    int row = rg*8 + cg;
    u64 kv = ((u64)map_f32(myv) << 32) | (u32)(~(u32)myi);
    atomicMax(&key_cur[row], kv);
  }
}

// ---------------- final token (step T-1) -------------------------------------------------
__global__ void k_final(const int* __restrict__ gnp, const int* __restrict__ input_x,
                        const u64* __restrict__ key_last, int* __restrict__ out) {
  int b = threadIdx.x;
  int gn = *gnp;
  int tk;
  if (Tz - 1 < gn) tk = input_x[b*Tz + Tz - 1];
  else             tk = (int)(~(u32)(key_last[b] & 0xFFFFFFFFull));
  out[b*Tz + Tz - 1] = tk;
}

extern "C" void kernel_launch(void* const* d_in, const int* in_sizes, int n_in,
                              void* d_out, int out_size, void* d_ws, size_t ws_size,
                              hipStream_t stream) {
  const int*   input_x   = (const int*)d_in[0];
  const int*   gnp       = (const int*)d_in[1];
  const int*   start_tok = (const int*)d_in[2];
  const float* emb = (const float*)d_in[3];
  const float* Wi  = (const float*)d_in[4];
  const float* Ui  = (const float*)d_in[5];
  const float* bi  = (const float*)d_in[6];
  const float* Wf  = (const float*)d_in[7];
  const float* Uf  = (const float*)d_in[8];
  const float* bff = (const float*)d_in[9];
  const float* Wog = (const float*)d_in[10];
  const float* Uog = (const float*)d_in[11];
  const float* bog = (const float*)d_in[12];
  const float* Wc  = (const float*)d_in[13];
  const float* Uc  = (const float*)d_in[14];
  const float* bc  = (const float*)d_in[15];
  const float* Wo  = (const float*)d_in[16];
  const float* bo  = (const float*)d_in[17];
  int* out = (int*)d_out;

  float* wsf = (float*)d_ws;
  float* cT  = wsf;                      // 16384 f
  u64*   key = (u64*)(wsf + 16384);      // 128 u64 = 256 f
  float* P4  = wsf + 16640;              // 327680 f
  float* hTR = wsf + 344320;             // 2 parities x 64 replicas x 16384 f = 8 MB

  size_t gsm = (size_t)KTOT * Bz * 4;        // 81920 B
  size_t lsm = (size_t)(16384 + 16384) * 4;  // 131072 B
  hipFuncSetAttribute((const void*)k_gates,
                      hipFuncAttributeMaxDynamicSharedMemorySize, (int)gsm);
  hipFuncSetAttribute((const void*)k_logits,
                      hipFuncAttributeMaxDynamicSharedMemorySize, (int)lsm);

  k_prep<<<dim3(256), dim3(320), 0, stream>>>(Wi, Ui, Wf, Uf, Wog, Uog, Wc, Uc, P4, key);

  for (int t = 0; t < Tz; ++t) {
    const float* hTR_prev = hTR + (size_t)((t + 1) & 1) * PARF;
    float*       hTR_cur  = hTR + (size_t)(t & 1) * PARF;
    const u64* key_prev = key + ((t + 1) & 1) * Bz;
    u64*       key_cur  = key + (t & 1) * Bz;
    k_gates<<<dim3(32), dim3(512), gsm, stream>>>(
        t, gnp, input_x, start_tok, emb, P4, bi, bff, bog, bc,
        hTR_prev, hTR_cur, cT, key_prev, key_cur, out);
    k_logits<<<dim3(250), dim3(512), lsm, stream>>>(
        t, gnp, hTR_cur, Wo, bo, key_cur);
  }
  k_final<<<dim3(1), dim3(64), 0, stream>>>(
      gnp, input_x, key + ((Tz - 1) & 1) * Bz, out);
}

// Round 12
// 731.349 us; speedup vs baseline: 1.3142x; 1.3142x over previous
//
#include <hip/hip_runtime.h>
#include <math.h>
#include <stdint.h>

#define Bz 64
#define Tz 32
#define Ez 64
#define Hz 256
#define Vz 32000
#define KTOT 320

typedef unsigned long long u64;
typedef unsigned int u32;

__device__ __forceinline__ u32 map_f32(float f) {
  u32 u = __float_as_uint(f);
  return (u & 0x80000000u) ? ~u : (u | 0x80000000u);
}

__device__ __forceinline__ void gload_lds16(const float* g, float* l) {
  __builtin_amdgcn_global_load_lds(
      (const __attribute__((address_space(1))) void*)g,
      (__attribute__((address_space(3))) void*)l, 16, 0, 0);
}

// ---------------- weight repack: P4[j][k][g] (g = i,f,o,c); zero key bufs ----------------
// (byte-identical to round 9's passing k_prep)
__global__ void k_prep(const float* __restrict__ Wi, const float* __restrict__ Ui,
                       const float* __restrict__ Wf, const float* __restrict__ Uf,
                       const float* __restrict__ Wog, const float* __restrict__ Uog,
                       const float* __restrict__ Wc, const float* __restrict__ Uc,
                       float* __restrict__ P4, u64* __restrict__ key) {
  int j = blockIdx.x;        // 0..255
  int k = threadIdx.x;       // 0..319
  float g0, g1, g2, g3;
  if (k < Ez) {
    g0 = Wi[k*Hz + j]; g1 = Wf[k*Hz + j]; g2 = Wog[k*Hz + j]; g3 = Wc[k*Hz + j];
  } else {
    int kk = k - Ez;
    g0 = Ui[kk*Hz + j]; g1 = Uf[kk*Hz + j]; g2 = Uog[kk*Hz + j]; g3 = Uc[kk*Hz + j];
  }
  float* p = P4 + ((size_t)j*KTOT + k)*4;
  p[0] = g0; p[1] = g1; p[2] = g2; p[3] = g3;
  if (j == 0 && k < 2*Bz) key[k] = 0ull;
}

// ---------------- per-step LSTM cell: 64 blocks x 512 thr ---------------------------------
// Block owns 4 j's. Wave = (j4 = wid>>1, seg = wid&1 -> k-half). lane = b.
// xh[320][64] + this block's packed weights in LDS; seg partials merged via LDS.
__global__ __launch_bounds__(512) void k_gates(
    int t, const int* __restrict__ gnp,
    const int* __restrict__ input_x, const int* __restrict__ start_tok,
    const float* __restrict__ emb, const float* __restrict__ P4,
    const float* __restrict__ bi_, const float* __restrict__ bf_,
    const float* __restrict__ bog_, const float* __restrict__ bc_,
    const float* __restrict__ hT_in, float* __restrict__ hT_out,
    float* __restrict__ cT,
    const u64* __restrict__ key_prev, u64* __restrict__ key_cur,
    int* __restrict__ out) {
  extern __shared__ float sm[];
  float* xh = sm;                        // 20480 f : [320][64] transposed
  float* pw = sm + 20480;                // 5120 f  : 4 j x 1280 (k*4+g)
  float* sc = sm + 25600;                // 1024 f  : merge [j4][g][b]
  int*   tok_s = (int*)(sm + 26624);     // 64

  int tid = threadIdx.x;
  int blk = blockIdx.x;
  int gn = *gnp;

  // ---- token select (R9 semantics) ----
  if (tid < Bz) {
    int b = tid, tk;
    if (t == 0)          tk = start_tok[b];
    else if (t - 1 < gn) tk = input_x[b*Tz + (t-1)];
    else                 tk = (int)(~(u32)(key_prev[b] & 0xFFFFFFFFull));
    tok_s[b] = tk;
    if (blk == 0 && t > 0) out[b*Tz + (t-1)] = tk;
  }
  if (blk == 0 && tid >= 64 && tid < 64 + Bz) key_cur[tid - 64] = 0ull;
  __syncthreads();

  // ---- stage x = emb[tok] transposed (same pattern as R9) ----
  {
    int b = tid & 63, part = tid >> 6;           // part 0..7 -> k = part*8..+7
    const float4* e4 = (const float4*)(emb + (size_t)tok_s[b]*Ez + part*8);
    float4 v0 = e4[0], v1 = e4[1];
    int k0 = part*8;
    xh[(k0+0)*Bz + b] = v0.x; xh[(k0+1)*Bz + b] = v0.y;
    xh[(k0+2)*Bz + b] = v0.z; xh[(k0+3)*Bz + b] = v0.w;
    xh[(k0+4)*Bz + b] = v1.x; xh[(k0+5)*Bz + b] = v1.y;
    xh[(k0+6)*Bz + b] = v1.z; xh[(k0+7)*Bz + b] = v1.w;
  }
  // ---- stage h (already [j][b]) ----
  if (t > 0) {
    const float4* s4 = (const float4*)hT_in;
    float4* d4 = (float4*)(xh + Ez*Bz);
    #pragma unroll
    for (int i = 0; i < 8; ++i) d4[tid + i*512] = s4[tid + i*512];
  }
  // ---- stage this block's 4-j weight slice (contiguous 5120 f) ----
  {
    const float* psrc = P4 + (size_t)blk*5120;
    #pragma unroll
    for (int i = 0; i < 10; ++i) pw[tid + i*512] = psrc[tid + i*512];
  }
  __syncthreads();

  // ---- dot: thread (j4, seg, b) computes 4 gates of (b, j) over its k-half ----
  int wid = tid >> 6, lane = tid & 63;
  int j4 = wid >> 1, seg = wid & 1;
  int j = blk*4 + j4;
  const float* wrow = pw + j4*1280;
  int kbeg = seg ? 160 : 0;
  int kend = (t > 0) ? (seg ? 320 : 160) : (seg ? 0 : 64);

  float ai = 0.f, af = 0.f, ao = 0.f, ac = 0.f;
  #pragma unroll 2
  for (int k = kbeg; k < kend; k += 4) {
    #pragma unroll
    for (int kk = 0; kk < 4; ++kk) {
      float4 wv = *(const float4*)(wrow + (k+kk)*4);
      float xv = xh[(k+kk)*Bz + lane];
      ai = fmaf(xv, wv.x, ai); af = fmaf(xv, wv.y, af);
      ao = fmaf(xv, wv.z, ao); ac = fmaf(xv, wv.w, ac);
    }
  }

  if (seg == 1) {
    sc[j4*256 +   0 + lane] = ai;
    sc[j4*256 +  64 + lane] = af;
    sc[j4*256 + 128 + lane] = ao;
    sc[j4*256 + 192 + lane] = ac;
  }
  __syncthreads();
  if (seg == 0) {
    ai += sc[j4*256 +   0 + lane] + bi_[j];
    af += sc[j4*256 +  64 + lane] + bf_[j];
    ao += sc[j4*256 + 128 + lane] + bog_[j];
    ac += sc[j4*256 + 192 + lane] + bc_[j];
    float gi = 1.f/(1.f + expf(-ai));
    float gf = 1.f/(1.f + expf(-af));
    float go = 1.f/(1.f + expf(-ao));
    float gc = tanhf(ac);
    float cold = (t > 0) ? cT[j*Bz + lane] : 0.f;
    float cn = gf*cold + gi*gc;
    float hn = go * tanhf(cn);
    cT[j*Bz + lane]     = cn;
    hT_out[j*Bz + lane] = hn;
  }
}

// ---------------- logits: 250 blocks x 512 thr; barrier-free per-wave k-pipelines --------
// (byte-identical to round 9's passing k_logits)
__global__ __launch_bounds__(512, 1) void k_logits(
    int t, const int* __restrict__ gnp,
    const float* __restrict__ hT,        // [k][b]
    const float* __restrict__ Wo, const float* __restrict__ bo,
    u64* __restrict__ key_cur) {         // 64 slots
  int gn = *gnp;
  if (t < gn) return;                    // uniform early-exit (teacher step)
  extern __shared__ float sm[];
  float* hLDS = sm;                      // 16384 f (64 KB)
  float* wbuf = sm + 16384;              // 16384 f (64 KB): 8 waves x 2 x 1024

  int tid = threadIdx.x;
  int bid = blockIdx.x;
  int wid = tid >> 6, lane = tid & 63;
  int seg = wid >> 1, chalf = wid & 1;
  int rg = lane >> 3, cg = lane & 7;

  float bo8[8];
  {
    const float4* b4 = (const float4*)(bo + bid*128 + chalf*64 + cg*8);
    float4 x = b4[0], y = b4[1];
    bo8[0]=x.x; bo8[1]=x.y; bo8[2]=x.z; bo8[3]=x.w;
    bo8[4]=y.x; bo8[5]=y.y; bo8[6]=y.z; bo8[7]=y.w;
  }
  // stage hT -> hLDS (coalesced)
  {
    const float4* s4 = (const float4*)hT;
    float4* d4 = (float4*)hLDS;
    #pragma unroll
    for (int i = 0; i < 8; ++i) d4[tid + i*512] = s4[tid + i*512];
  }
  __syncthreads();

  float acc[8][8] = {};
  float* wb = wbuf + wid*2048;
  const float* gW = Wo + bid*128;

#define STAGE(q_, p_) { \
    int kb = seg*64 + (q_)*8; \
    _Pragma("unroll") \
    for (int i = 0; i < 4; ++i) { \
      int row = kb + i*2 + (lane>>5); \
      gload_lds16(gW + (size_t)row*Vz + ((lane&31)<<2), wb + (p_)*1024 + i*256); \
    } }

#define COMPUTE(q_, p_) { \
    const float* wp = wb + (p_)*1024; \
    const float* hp = hLDS + (seg*64 + (q_)*8)*Bz + rg*8; \
    _Pragma("unroll") \
    for (int kk = 0; kk < 8; ++kk) { \
      float4 h0 = *(const float4*)(hp + kk*Bz); \
      float4 h1 = *(const float4*)(hp + kk*Bz + 4); \
      float4 w0 = *(const float4*)(wp + kk*128 + chalf*64 + cg*8); \
      float4 w1 = *(const float4*)(wp + kk*128 + chalf*64 + cg*8 + 4); \
      float hv[8] = {h0.x,h0.y,h0.z,h0.w,h1.x,h1.y,h1.z,h1.w}; \
      float wv[8] = {w0.x,w0.y,w0.z,w0.w,w1.x,w1.y,w1.z,w1.w}; \
      _Pragma("unroll") \
      for (int r = 0; r < 8; ++r) { \
        _Pragma("unroll") \
        for (int c = 0; c < 8; ++c) acc[r][c] = fmaf(hv[r], wv[c], acc[r][c]); } \
    } }

  STAGE(0, 0)
  #pragma unroll 1
  for (int q = 0; q < 7; ++q) {
    STAGE(q+1, (q+1)&1)
    asm volatile("s_waitcnt vmcnt(4)" ::: "memory");   // oldest chunk landed; newest in flight
    __builtin_amdgcn_sched_barrier(0);
    COMPUTE(q, q&1)
  }
  asm volatile("s_waitcnt vmcnt(0)" ::: "memory");
  __builtin_amdgcn_sched_barrier(0);
  COMPUTE(7, 1)
#undef STAGE
#undef COMPUTE

  // ---- merge k-segment partials: (seg2,seg3) -> (seg0,seg1), then seg1 -> seg0 ----
  float* scratch = wbuf;                 // 4 regions x 4096 f
  __syncthreads();                       // all waves done with private wbuf
  if (wid >= 4) {
    float* r = scratch + (wid-4)*4096;
    #pragma unroll
    for (int i = 0; i < 64; ++i) r[i*64 + lane] = acc[i>>3][i&7];
  }
  __syncthreads();
  if (wid < 4) {
    const float* r = scratch + wid*4096;
    #pragma unroll
    for (int i = 0; i < 64; ++i) acc[i>>3][i&7] += r[i*64 + lane];
  }
  __syncthreads();
  if (wid == 2 || wid == 3) {
    float* r = scratch + (wid-2)*4096;
    #pragma unroll
    for (int i = 0; i < 64; ++i) r[i*64 + lane] = acc[i>>3][i&7];
  }
  __syncthreads();

  if (wid < 2) {
    const float* r = scratch + wid*4096;
    #pragma unroll
    for (int i = 0; i < 64; ++i) acc[i>>3][i&7] += r[i*64 + lane];

    // per-row argmax over this wave's 64 cols; first-index-wins
    int cbase = bid*128 + chalf*64 + cg*8;
    float myv = 0.f; int myi = 0;
    #pragma unroll
    for (int rr = 0; rr < 8; ++rr) {
      float bv = acc[rr][0] + bo8[0]; int bix = cbase;
      #pragma unroll
      for (int c = 1; c < 8; ++c) {
        float v = acc[rr][c] + bo8[c];
        if (v > bv) { bv = v; bix = cbase + c; }
      }
      #pragma unroll
      for (int m = 1; m < 8; m <<= 1) {
        float ov = __shfl_xor(bv, m, 64);
        int   oi = __shfl_xor(bix, m, 64);
        if (ov > bv || (ov == bv && oi < bix)) { bv = ov; bix = oi; }
      }
      if (cg == rr) { myv = bv; myi = bix; }
    }
    int row = rg*8 + cg;
    u64 kv = ((u64)map_f32(myv) << 32) | (u32)(~(u32)myi);
    atomicMax(&key_cur[row], kv);
  }
}

// ---------------- final token (step T-1) -------------------------------------------------
// (byte-identical to round 9's passing k_final)
__global__ void k_final(const int* __restrict__ gnp, const int* __restrict__ input_x,
                        const u64* __restrict__ key_last, int* __restrict__ out) {
  int b = threadIdx.x;
  int gn = *gnp;
  int tk;
  if (Tz - 1 < gn) tk = input_x[b*Tz + Tz - 1];
  else             tk = (int)(~(u32)(key_last[b] & 0xFFFFFFFFull));
  out[b*Tz + Tz - 1] = tk;
}

extern "C" void kernel_launch(void* const* d_in, const int* in_sizes, int n_in,
                              void* d_out, int out_size, void* d_ws, size_t ws_size,
                              hipStream_t stream) {
  const int*   input_x   = (const int*)d_in[0];
  const int*   gnp       = (const int*)d_in[1];
  const int*   start_tok = (const int*)d_in[2];
  const float* emb = (const float*)d_in[3];
  const float* Wi  = (const float*)d_in[4];
  const float* Ui  = (const float*)d_in[5];
  const float* bi  = (const float*)d_in[6];
  const float* Wf  = (const float*)d_in[7];
  const float* Uf  = (const float*)d_in[8];
  const float* bff = (const float*)d_in[9];
  const float* Wog = (const float*)d_in[10];
  const float* Uog = (const float*)d_in[11];
  const float* bog = (const float*)d_in[12];
  const float* Wc  = (const float*)d_in[13];
  const float* Uc  = (const float*)d_in[14];
  const float* bc  = (const float*)d_in[15];
  const float* Wo  = (const float*)d_in[16];
  const float* bo  = (const float*)d_in[17];
  int* out = (int*)d_out;

  float* wsf = (float*)d_ws;
  float* hTA = wsf;                      // 16384 f
  float* hTB = wsf + 16384;              // 16384 f
  float* cT  = wsf + 32768;              // 16384 f
  u64*   key = (u64*)(wsf + 49152);      // 128 u64 = 256 f
  float* P4  = wsf + 49152 + 256;        // 327680 f

  size_t gsm = (size_t)(20480 + 5120 + 1024 + 64) * 4;   // 106752 B
  size_t lsm = (size_t)(16384 + 16384) * 4;              // 131072 B
  hipFuncSetAttribute((const void*)k_gates,
                      hipFuncAttributeMaxDynamicSharedMemorySize, (int)gsm);
  hipFuncSetAttribute((const void*)k_logits,
                      hipFuncAttributeMaxDynamicSharedMemorySize, (int)lsm);

  k_prep<<<dim3(256), dim3(320), 0, stream>>>(Wi, Ui, Wf, Uf, Wog, Uog, Wc, Uc, P4, key);

  for (int t = 0; t < Tz; ++t) {
    const float* hT_in  = (t & 1) ? hTA : hTB;
    float*       hT_out = (t & 1) ? hTB : hTA;
    const u64* key_prev = key + ((t + 1) & 1) * Bz;
    u64*       key_cur  = key + (t & 1) * Bz;
    k_gates<<<dim3(64), dim3(512), gsm, stream>>>(
        t, gnp, input_x, start_tok, emb, P4, bi, bff, bog, bc,
        hT_in, hT_out, cT, key_prev, key_cur, out);
    k_logits<<<dim3(250), dim3(512), lsm, stream>>>(
        t, gnp, hT_out, Wo, bo, key_cur);
  }
  k_final<<<dim3(1), dim3(64), 0, stream>>>(
      gnp, input_x, key + ((Tz - 1) & 1) * Bz, out);
}